// Round 13
// baseline (432.477 us; speedup 1.0000x reference)
//
#include <hip/hip_runtime.h>

#define THREADS 256
#define P2T 512
#define P1B 1024    // p1 blocks inside fusedA
#define CVTXB 1536  // cvtX blocks (grid-stride; ~8 chunks/thread at N=100K)

typedef __attribute__((ext_vector_type(8))) short short8;
typedef __attribute__((ext_vector_type(4))) float f32x4;

__device__ __forceinline__ unsigned short f2bf(float f) {
    unsigned u = __builtin_bit_cast(unsigned, f);
    return (unsigned short)((u + 0x7FFFu + ((u >> 16) & 1u)) >> 16);  // RNE
}
__device__ __forceinline__ float bf2f_lo(unsigned u) { return __builtin_bit_cast(float, u << 16); }
__device__ __forceinline__ float bf2f_hi(unsigned u) { return __builtin_bit_cast(float, u & 0xFFFF0000u); }

// ---------------- fused: p1 counting-sort pass | W pack | x convert ----------------
// cvtX is a grid-stride loop (r12 lesson: 12500 one-shot blocks with a single
// load each = zero MLP, latency-bound tail; a loop gives ~8 in-flight loads).
__global__ void fusedA_kernel(const int* __restrict__ row, const int* __restrict__ col,
                              const float* __restrict__ val, int* __restrict__ gcur,
                              uint2* __restrict__ estage,
                              const float* __restrict__ W, unsigned short* __restrict__ WbP,
                              const float4* __restrict__ x, uint4* __restrict__ xb,
                              int n_edges, int nbkt, int capS, int n8) {
    int b = blockIdx.x, tid = threadIdx.x;
    if (b < P1B) {
        __shared__ int h[512];
        __shared__ int curl[512];
        int g = b & 7;
        int E0 = (int)((long long)b * n_edges / P1B);
        int E1 = (int)((long long)(b + 1) * n_edges / P1B);
        for (int i = tid; i < 512; i += THREADS) h[i] = 0;
        __syncthreads();
        for (int e = E0 + tid; e < E1; e += THREADS)
            atomicAdd(&h[row[e] >> 8], 1);
        __syncthreads();
        for (int bk = tid; bk < nbkt; bk += THREADS) {
            int c = h[bk];
            curl[bk] = (bk * 8 + g) * capS + (c ? atomicAdd(&gcur[bk * 8 + g], c) : 0);
        }
        __syncthreads();
        for (int e = E0 + tid; e < E1; e += THREADS) {
            int r = row[e];
            int bk = r >> 8;
            int pos = atomicAdd(&curl[bk], 1);      // LDS atomic -> global position
            if (pos < (bk * 8 + g + 1) * capS)      // overflow guard
                estage[pos] = make_uint2(((unsigned)(r & 255) << 24) | (unsigned)col[e],
                                         (unsigned)__float_as_int(val[e]));
        }
    } else if (b < P1B + 32) {
        int f = (b - P1B) * THREADS + tid;          // 8192 frags
        int l = f & 63, nt = (f >> 6) & 15, k0i = f >> 10;
        int r = nt * 16 + (l & 15);
        int koff = k0i * 32 + 8 * (l >> 4);
        const float4* s = reinterpret_cast<const float4*>(W + r * 256 + koff);
        float4 a = s[0], bb = s[1];
        uint4 o;
        o.x = (unsigned)f2bf(a.x) | ((unsigned)f2bf(a.y) << 16);
        o.y = (unsigned)f2bf(a.z) | ((unsigned)f2bf(a.w) << 16);
        o.z = (unsigned)f2bf(bb.x) | ((unsigned)f2bf(bb.y) << 16);
        o.w = (unsigned)f2bf(bb.z) | ((unsigned)f2bf(bb.w) << 16);
        reinterpret_cast<uint4*>(WbP)[f] = o;
    } else {
        // ---- cvtX: grid-stride, ~8 chunks/thread -> 8 loads in flight ----
        int stride = CVTXB * THREADS;
        for (int i = (b - P1B - 32) * THREADS + tid; i < n8; i += stride) {
            float4 a = x[2 * i], bb = x[2 * i + 1];
            uint4 o;
            o.x = (unsigned)f2bf(a.x) | ((unsigned)f2bf(a.y) << 16);
            o.y = (unsigned)f2bf(a.z) | ((unsigned)f2bf(a.w) << 16);
            o.z = (unsigned)f2bf(bb.x) | ((unsigned)f2bf(bb.y) << 16);
            o.w = (unsigned)f2bf(bb.z) | ((unsigned)f2bf(bb.w) << 16);
            reinterpret_cast<uint4*>(xb)[i] = o;
        }
    }
}

// ---------------- p2: per-bucket sort -> CSR over 8 XCD sub-regions ----------------
__global__ void p2_sort(const uint2* __restrict__ estage, const int* __restrict__ gcur,
                        int2* __restrict__ pr, int* __restrict__ offs,
                        int capS, int n_nodes, int nbkt) {
    __shared__ int red[P2T];
    __shared__ int h[256];
    __shared__ int curh[256];
    __shared__ int wsum[4];
    __shared__ int scnt[8];
    int b = blockIdx.x, tid = threadIdx.x;

    int lim = b * 8;
    int partial = 0;
    for (int j = tid; j < lim; j += P2T) {
        int c = gcur[j];
        partial += c > capS ? capS : c;
    }
    red[tid] = partial;
    __syncthreads();
    #pragma unroll
    for (int s = P2T / 2; s > 0; s >>= 1) {
        if (tid < s) red[tid] += red[tid + s];
        __syncthreads();
    }
    int gb = red[0];
    if (tid < 8) {
        int c = gcur[b * 8 + tid];
        scnt[tid] = c > capS ? capS : c;
    }
    if (tid < 256) h[tid] = 0;
    __syncthreads();

    #pragma unroll
    for (int g = 0; g < 8; ++g) {
        int cnt = scnt[g];
        int base = (b * 8 + g) * capS;
        for (int i = tid; i < cnt; i += P2T)
            atomicAdd(&h[estage[base + i].x >> 24], 1);
    }
    __syncthreads();
    if (tid < 256) {
        int v = h[tid];
        int lane = tid & 63, w = tid >> 6;
        int incl = v;
        #pragma unroll
        for (int off = 1; off < 64; off <<= 1) {
            int t = __shfl_up(incl, off, 64);
            if (lane >= off) incl += t;
        }
        if (lane == 63) wsum[w] = incl;
        __syncthreads();
        int wo = 0;
        for (int i = 0; i < w; ++i) wo += wsum[i];
        int excl = wo + incl - v;
        int node = b * 256 + tid;
        if (node < n_nodes) offs[node] = gb + excl;
        curh[tid] = gb + excl;
    } else {
        __syncthreads();
    }
    if (b == nbkt - 1 && tid == 0) {
        int t = 0;
        #pragma unroll
        for (int g = 0; g < 8; ++g) t += scnt[g];
        offs[n_nodes] = gb + t;
    }
    __syncthreads();
    #pragma unroll
    for (int g = 0; g < 8; ++g) {
        int cnt = scnt[g];
        int base = (b * 8 + g) * capS;
        for (int i = tid; i < cnt; i += P2T) {
            uint2 p = estage[base + i];
            int q = atomicAdd(&curh[(int)(p.x >> 24)], 1);   // LDS atomic
            pr[q] = make_int2((int)(p.x & 0x00FFFFFFu), (int)p.y);
        }
    }
}

// ---------------- SpMM: one wave64 per node; bucket-range [b0,b1) per dispatch --------
template<int OUT_BF16>
__global__ void spmm_bf16_kernel(const uint2* __restrict__ xb, const int* __restrict__ offs,
                                 const int2* __restrict__ pr, void* __restrict__ outp,
                                 int b0, int b1, int nnodes) {
    int g = blockIdx.x & 7;
    int inst = blockIdx.x >> 3;
    int bkt = b0 + g + 8 * (inst >> 6);
    if (bkt >= b1) return;
    int wid = bkt * 256 + (inst & 63) * 4 + (threadIdx.x >> 6);
    int lane = threadIdx.x & 63;
    if (wid >= nnodes) return;
    int s = offs[wid], e = offs[wid + 1];
    float a0 = 0.f, a1 = 0.f, a2 = 0.f, a3 = 0.f;
    int i = s;
    if (i < e && (i & 1)) {
        int2 p = pr[i];
        uint2 xv = xb[(size_t)p.x * 64 + lane];
        float v = __int_as_float(p.y);
        a0 = fmaf(v, bf2f_lo(xv.x), a0); a1 = fmaf(v, bf2f_hi(xv.x), a1);
        a2 = fmaf(v, bf2f_lo(xv.y), a2); a3 = fmaf(v, bf2f_hi(xv.y), a3);
        ++i;
    }
    for (; i + 8 <= e; i += 8) {
        int4 pa = *reinterpret_cast<const int4*>(pr + i);
        int4 pb = *reinterpret_cast<const int4*>(pr + i + 2);
        int4 pc = *reinterpret_cast<const int4*>(pr + i + 4);
        int4 pd = *reinterpret_cast<const int4*>(pr + i + 6);
        uint2 x0 = xb[(size_t)pa.x * 64 + lane];
        uint2 x1 = xb[(size_t)pa.z * 64 + lane];
        uint2 x2 = xb[(size_t)pb.x * 64 + lane];
        uint2 x3 = xb[(size_t)pb.z * 64 + lane];
        uint2 x4_ = xb[(size_t)pc.x * 64 + lane];
        uint2 x5 = xb[(size_t)pc.z * 64 + lane];
        uint2 x6 = xb[(size_t)pd.x * 64 + lane];
        uint2 x7 = xb[(size_t)pd.z * 64 + lane];
        float v0 = __int_as_float(pa.y), v1 = __int_as_float(pa.w);
        float v2 = __int_as_float(pb.y), v3 = __int_as_float(pb.w);
        float v4 = __int_as_float(pc.y), v5 = __int_as_float(pc.w);
        float v6 = __int_as_float(pd.y), v7 = __int_as_float(pd.w);
        a0 = fmaf(v0, bf2f_lo(x0.x), a0); a1 = fmaf(v0, bf2f_hi(x0.x), a1);
        a2 = fmaf(v0, bf2f_lo(x0.y), a2); a3 = fmaf(v0, bf2f_hi(x0.y), a3);
        a0 = fmaf(v1, bf2f_lo(x1.x), a0); a1 = fmaf(v1, bf2f_hi(x1.x), a1);
        a2 = fmaf(v1, bf2f_lo(x1.y), a2); a3 = fmaf(v1, bf2f_hi(x1.y), a3);
        a0 = fmaf(v2, bf2f_lo(x2.x), a0); a1 = fmaf(v2, bf2f_hi(x2.x), a1);
        a2 = fmaf(v2, bf2f_lo(x2.y), a2); a3 = fmaf(v2, bf2f_hi(x2.y), a3);
        a0 = fmaf(v3, bf2f_lo(x3.x), a0); a1 = fmaf(v3, bf2f_hi(x3.x), a1);
        a2 = fmaf(v3, bf2f_lo(x3.y), a2); a3 = fmaf(v3, bf2f_hi(x3.y), a3);
        a0 = fmaf(v4, bf2f_lo(x4_.x), a0); a1 = fmaf(v4, bf2f_hi(x4_.x), a1);
        a2 = fmaf(v4, bf2f_lo(x4_.y), a2); a3 = fmaf(v4, bf2f_hi(x4_.y), a3);
        a0 = fmaf(v5, bf2f_lo(x5.x), a0); a1 = fmaf(v5, bf2f_hi(x5.x), a1);
        a2 = fmaf(v5, bf2f_lo(x5.y), a2); a3 = fmaf(v5, bf2f_hi(x5.y), a3);
        a0 = fmaf(v6, bf2f_lo(x6.x), a0); a1 = fmaf(v6, bf2f_hi(x6.x), a1);
        a2 = fmaf(v6, bf2f_lo(x6.y), a2); a3 = fmaf(v6, bf2f_hi(x6.y), a3);
        a0 = fmaf(v7, bf2f_lo(x7.x), a0); a1 = fmaf(v7, bf2f_hi(x7.x), a1);
        a2 = fmaf(v7, bf2f_lo(x7.y), a2); a3 = fmaf(v7, bf2f_hi(x7.y), a3);
    }
    for (; i + 2 <= e; i += 2) {
        int4 pa = *reinterpret_cast<const int4*>(pr + i);
        uint2 x0 = xb[(size_t)pa.x * 64 + lane];
        uint2 x1 = xb[(size_t)pa.z * 64 + lane];
        float v0 = __int_as_float(pa.y), v1 = __int_as_float(pa.w);
        a0 = fmaf(v0, bf2f_lo(x0.x), a0); a1 = fmaf(v0, bf2f_hi(x0.x), a1);
        a2 = fmaf(v0, bf2f_lo(x0.y), a2); a3 = fmaf(v0, bf2f_hi(x0.y), a3);
        a0 = fmaf(v1, bf2f_lo(x1.x), a0); a1 = fmaf(v1, bf2f_hi(x1.x), a1);
        a2 = fmaf(v1, bf2f_lo(x1.y), a2); a3 = fmaf(v1, bf2f_hi(x1.y), a3);
    }
    for (; i < e; ++i) {
        int2 p = pr[i];
        uint2 xv = xb[(size_t)p.x * 64 + lane];
        float v = __int_as_float(p.y);
        a0 = fmaf(v, bf2f_lo(xv.x), a0); a1 = fmaf(v, bf2f_hi(xv.x), a1);
        a2 = fmaf(v, bf2f_lo(xv.y), a2); a3 = fmaf(v, bf2f_hi(xv.y), a3);
    }
    if (OUT_BF16) {
        ushort4 o;
        o.x = f2bf(a0); o.y = f2bf(a1); o.z = f2bf(a2); o.w = f2bf(a3);
        *reinterpret_cast<ushort4*>((unsigned short*)outp + (size_t)wid * 256 + 4 * lane) = o;
    } else {
        ((float4*)outp)[(size_t)wid * 64 + lane] = make_float4(a0, a1, a2, a3);
    }
}

__global__ void spmm_f32_kernel(const float4* __restrict__ x4, const int* __restrict__ offs,
                                const int2* __restrict__ pr, float4* __restrict__ out4,
                                int nnodes) {
    int wid = (blockIdx.x * blockDim.x + threadIdx.x) >> 6;
    int lane = threadIdx.x & 63;
    if (wid >= nnodes) return;
    int s = offs[wid], e = offs[wid + 1];
    float4 acc = make_float4(0.f, 0.f, 0.f, 0.f);
    for (int i = s; i < e; ++i) {
        int2 p = pr[i];
        float4 xv = x4[(size_t)p.x * 64 + lane];
        float v = __int_as_float(p.y);
        acc.x = fmaf(v, xv.x, acc.x); acc.y = fmaf(v, xv.y, acc.y);
        acc.z = fmaf(v, xv.z, acc.z); acc.w = fmaf(v, xv.w, acc.w);
    }
    out4[(size_t)wid * 64 + lane] = acc;
}

// ---------------- gemm_direct3: 2 row-tiles share B-frags, N-split keeps VGPR low ----
__launch_bounds__(256)
__global__ void gemm_direct3_kernel(const unsigned short* __restrict__ aggb,
                                    const unsigned short* __restrict__ WbP,
                                    const float* __restrict__ bias,
                                    float* __restrict__ out, int n) {
    int tid = threadIdx.x, lane = tid & 63, w = tid >> 6;
    int row0 = blockIdx.x * 128 + w * 32;
    int lr = lane & 15, lg = lane >> 4;
    const unsigned short* arow0 = aggb + (size_t)(row0 + lr) * 256 + lg * 8;
    const unsigned short* arow1 = arow0 + 16 * 256;
    short8 af0[8], af1[8];
    #pragma unroll
    for (int k = 0; k < 8; ++k) {
        af0[k] = *reinterpret_cast<const short8*>(arow0 + k * 32);
        af1[k] = *reinterpret_cast<const short8*>(arow1 + k * 32);
    }
    #pragma unroll
    for (int half = 0; half < 2; ++half) {
        f32x4 acc0[8], acc1[8];
        #pragma unroll
        for (int nt = 0; nt < 8; ++nt) {
            acc0[nt] = (f32x4){0.f, 0.f, 0.f, 0.f};
            acc1[nt] = (f32x4){0.f, 0.f, 0.f, 0.f};
        }
        #pragma unroll
        for (int k = 0; k < 8; ++k) {
            #pragma unroll
            for (int nt = 0; nt < 8; ++nt) {
                short8 bf_ = *reinterpret_cast<const short8*>(
                    &WbP[(size_t)((k * 16 + half * 8 + nt) * 64 + lane) * 8]);
                acc0[nt] = __builtin_amdgcn_mfma_f32_16x16x32_bf16(af0[k], bf_, acc0[nt], 0, 0, 0);
                acc1[nt] = __builtin_amdgcn_mfma_f32_16x16x32_bf16(af1[k], bf_, acc1[nt], 0, 0, 0);
            }
        }
        #pragma unroll
        for (int nt = 0; nt < 8; ++nt) {
            int gc = half * 128 + nt * 16 + lr;
            float bv = bias[gc];
            #pragma unroll
            for (int q = 0; q < 4; ++q) {
                int gr0 = row0 + lg * 4 + q;
                int gr1 = gr0 + 16;
                if (gr0 < n) out[(size_t)gr0 * 256 + gc] = acc0[nt][q] + bv;
                if (gr1 < n) out[(size_t)gr1 * 256 + gc] = acc1[nt][q] + bv;
            }
        }
    }
}

// ---------------- fallback tier (round-4 path) ----------------

__global__ void zero_kernel(int* __restrict__ p, int n) {
    int i = blockIdx.x * blockDim.x + threadIdx.x;
    if (i < n) p[i] = 0;
}

__global__ void hist_part_kernel(const int* __restrict__ row, int* __restrict__ cnt,
                                 int n_edges, int n_nodes) {
    int g = blockIdx.x & 7;
    int inst = blockIdx.x >> 3;
    int ninst = gridDim.x >> 3;
    int lo = (int)(((long long)g * n_nodes) >> 3);
    int hi = (int)(((long long)(g + 1) * n_nodes) >> 3);
    int e0 = (int)(((long long)inst * n_edges) / ninst);
    int e1 = (int)(((long long)(inst + 1) * n_edges) / ninst);
    for (int e = e0 + threadIdx.x; e < e1; e += THREADS) {
        int r = row[e];
        if (r >= lo && r < hi) atomicAdd(&cnt[r], 1);
    }
}

__global__ void place_part_kernel(const int* __restrict__ row, const int* __restrict__ col,
                                  const float* __restrict__ val, int* __restrict__ cur,
                                  int2* __restrict__ pr, int n_edges, int n_nodes) {
    int g = blockIdx.x & 7;
    int inst = blockIdx.x >> 3;
    int ninst = gridDim.x >> 3;
    int lo = (int)(((long long)g * n_nodes) >> 3);
    int hi = (int)(((long long)(g + 1) * n_nodes) >> 3);
    int e0 = (int)(((long long)inst * n_edges) / ninst);
    int e1 = (int)(((long long)(inst + 1) * n_edges) / ninst);
    for (int e = e0 + threadIdx.x; e < e1; e += THREADS) {
        int r = row[e];
        if (r >= lo && r < hi) {
            int p = atomicAdd(&cur[r], 1);
            pr[p] = make_int2(col[e], __float_as_int(val[e]));
        }
    }
}

__global__ void scan1_kernel(const int* __restrict__ cnt, int* __restrict__ offs,
                             int* __restrict__ bsum, int n) {
    int tid = threadIdx.x;
    int base = blockIdx.x * 1024 + tid * 4;
    int v0 = 0, v1 = 0, v2 = 0, v3 = 0;
    if (base + 3 < n) {
        int4 v = *reinterpret_cast<const int4*>(cnt + base);
        v0 = v.x; v1 = v.y; v2 = v.z; v3 = v.w;
    } else {
        if (base + 0 < n) v0 = cnt[base + 0];
        if (base + 1 < n) v1 = cnt[base + 1];
        if (base + 2 < n) v2 = cnt[base + 2];
    }
    int ts = v0 + v1 + v2 + v3;
    int lane = tid & 63;
    int incl = ts;
    #pragma unroll
    for (int off = 1; off < 64; off <<= 1) {
        int t = __shfl_up(incl, off, 64);
        if (lane >= off) incl += t;
    }
    __shared__ int wsum[4];
    int w = tid >> 6;
    if (lane == 63) wsum[w] = incl;
    __syncthreads();
    int wo = 0;
    for (int i = 0; i < w; ++i) wo += wsum[i];
    int excl = wo + incl - ts;
    if (base + 0 < n) offs[base + 0] = excl;
    if (base + 1 < n) offs[base + 1] = excl + v0;
    if (base + 2 < n) offs[base + 2] = excl + v0 + v1;
    if (base + 3 < n) offs[base + 3] = excl + v0 + v1 + v2;
    if (tid == THREADS - 1) bsum[blockIdx.x] = wo + incl;
}

__global__ void scan2_kernel(int* __restrict__ bsum, int nb) {
    int tid = threadIdx.x;
    int base = tid * 4;
    int v0 = 0, v1 = 0, v2 = 0, v3 = 0;
    if (base + 0 < nb) v0 = bsum[base + 0];
    if (base + 1 < nb) v1 = bsum[base + 1];
    if (base + 2 < nb) v2 = bsum[base + 2];
    if (base + 3 < nb) v3 = bsum[base + 3];
    int ts = v0 + v1 + v2 + v3;
    int lane = tid & 63;
    int incl = ts;
    #pragma unroll
    for (int off = 1; off < 64; off <<= 1) {
        int t = __shfl_up(incl, off, 64);
        if (lane >= off) incl += t;
    }
    __shared__ int wsum[4];
    int w = tid >> 6;
    if (lane == 63) wsum[w] = incl;
    __syncthreads();
    int wo = 0;
    for (int i = 0; i < w; ++i) wo += wsum[i];
    int excl = wo + incl - ts;
    if (base + 0 < nb) bsum[base + 0] = excl;
    if (base + 1 < nb) bsum[base + 1] = excl + v0;
    if (base + 2 < nb) bsum[base + 2] = excl + v0 + v1;
    if (base + 3 < nb) bsum[base + 3] = excl + v0 + v1 + v2;
    if (tid == THREADS - 1) bsum[nb] = wo + incl;
}

__global__ void scan3_kernel(int* __restrict__ offs, const int* __restrict__ bsum,
                             int* __restrict__ cur, int n) {
    int i = blockIdx.x * blockDim.x + threadIdx.x;
    if (i < n) {
        int v = offs[i] + bsum[i >> 10];
        offs[i] = v;
        cur[i] = v;
    }
    if (i == 0) offs[n] = bsum[(n + 1023) >> 10];
}

__global__ void cvt_bf16_kernel(const float4* __restrict__ in, uint4* __restrict__ out, int n8) {
    int i = blockIdx.x * blockDim.x + threadIdx.x;
    if (i >= n8) return;
    float4 a = in[2 * i], b = in[2 * i + 1];
    uint4 o;
    o.x = (unsigned)f2bf(a.x) | ((unsigned)f2bf(a.y) << 16);
    o.y = (unsigned)f2bf(a.z) | ((unsigned)f2bf(a.w) << 16);
    o.z = (unsigned)f2bf(b.x) | ((unsigned)f2bf(b.y) << 16);
    o.w = (unsigned)f2bf(b.z) | ((unsigned)f2bf(b.w) << 16);
    out[i] = o;
}

__launch_bounds__(256, 2)
__global__ void gemm_mfma_kernel(float* __restrict__ out, const unsigned short* __restrict__ Wb,
                                 const float* __restrict__ bias, int nrows) {
    __shared__ unsigned short As[64][264];
    __shared__ unsigned short Ws[256][40];
    int tid = threadIdx.x;
    int rowBase = blockIdx.x * 64;

    const float4* o4 = reinterpret_cast<const float4*>(out);
    for (int it = tid; it < 64 * 64; it += 256) {
        int r = it >> 6, c = it & 63;
        float4 v = make_float4(0.f, 0.f, 0.f, 0.f);
        int gr = rowBase + r;
        if (gr < nrows) v = o4[(size_t)gr * 64 + c];
        ushort4 w;
        w.x = f2bf(v.x); w.y = f2bf(v.y); w.z = f2bf(v.z); w.w = f2bf(v.w);
        *reinterpret_cast<ushort4*>(&As[r][c * 4]) = w;
    }

    int w = tid >> 6, lane = tid & 63;
    int lr = lane & 15, lg = lane >> 4;
    f32x4 acc[16];
    #pragma unroll
    for (int nt = 0; nt < 16; ++nt) acc[nt] = (f32x4){0.f, 0.f, 0.f, 0.f};

    for (int k0 = 0; k0 < 256; k0 += 32) {
        __syncthreads();
        for (int it = tid; it < 1024; it += 256) {
            int r = it >> 2, c = it & 3;
            uint4 v = *reinterpret_cast<const uint4*>(Wb + (size_t)r * 256 + k0 + c * 8);
            *reinterpret_cast<uint4*>(&Ws[r][c * 8]) = v;
        }
        __syncthreads();
        short8 af = *reinterpret_cast<const short8*>(&As[w * 16 + lr][k0 + 8 * lg]);
        #pragma unroll
        for (int nt = 0; nt < 16; ++nt) {
            short8 bf_ = *reinterpret_cast<const short8*>(&Ws[nt * 16 + lr][8 * lg]);
            acc[nt] = __builtin_amdgcn_mfma_f32_16x16x32_bf16(af, bf_, acc[nt], 0, 0, 0);
        }
    }

    #pragma unroll
    for (int nt = 0; nt < 16; ++nt) {
        int gc = nt * 16 + lr;
        float bv = bias[gc];
        #pragma unroll
        for (int q = 0; q < 4; ++q) {
            int gr = rowBase + w * 16 + lg * 4 + q;
            if (gr < nrows) out[(size_t)gr * 256 + gc] = acc[nt][q] + bv;
        }
    }
}

// ---------------- launch ----------------

extern "C" void kernel_launch(void* const* d_in, const int* in_sizes, int n_in,
                              void* d_out, int out_size, void* d_ws, size_t ws_size,
                              hipStream_t stream) {
    const float* x     = (const float*)d_in[0];
    const int*   erow  = (const int*)d_in[1];
    const int*   ecol  = (const int*)d_in[2];
    const float* evalv = (const float*)d_in[3];
    const float* W     = (const float*)d_in[4];
    const float* bias  = (const float*)d_in[5];
    float* out = (float*)d_out;

    int n_nodes = in_sizes[0] / 256;
    int n_edges = in_sizes[1];

    int nbkt = (n_nodes + 255) >> 8;
    int avg8 = n_edges / (8 * (nbkt > 0 ? nbkt : 1)) + 1;   // per (bucket,XCD) expected
    int capS = avg8 + avg8 / 8 + 512;                        // ~24-sigma overflow margin

    // ---- new-path workspace layout (int units) ----
    size_t A = (size_t)((n_nodes + 63) & ~63) + 64;       // offs: n+1
    int* offs  = (int*)d_ws;
    int* gcur  = offs + A;                                // 4096 sub-region cursors
    unsigned short* WbP = (unsigned short*)(gcur + 4096); // 32768 ints
    int2* pr = (int2*)(WbP + 65536);                      // E records
    int* after_pr = (int*)(pr + n_edges);

    size_t est_ints  = (size_t)nbkt * 8 * capS * 2;
    size_t aggb_ints = (size_t)n_nodes * 128 + 32768;     // +pad: gemm3 reads <=127 rows past n
    size_t xb_ints   = (size_t)n_nodes * 128;
    size_t alias_ints = est_ints > aggb_ints ? est_ints : aggb_ints;
    size_t head_ints = (size_t)(after_pr - (int*)d_ws);
    size_t need_new = (head_ints + alias_ints + xb_ints) * 4;
    bool new_ok = (nbkt <= 512) && (nbkt >= 1) && (n_nodes <= (1 << 24)) && ws_size >= need_new;

    if (new_ok) {
        uint2* estage = (uint2*)after_pr;
        unsigned short* aggb = (unsigned short*)after_pr;            // alias (estage dead post-p2)
        unsigned short* xb = (unsigned short*)(after_pr + alias_ints);

        hipMemsetAsync(gcur, 0, 4096 * sizeof(int), stream);
        int n8 = n_nodes * 32;
        fusedA_kernel<<<P1B + 32 + CVTXB, THREADS, 0, stream>>>(
            erow, ecol, evalv, gcur, estage, W, WbP, (const float4*)x, (uint4*)xb,
            n_edges, nbkt, capS, n8);
        p2_sort<<<nbkt, P2T, 0, stream>>>(estage, gcur, pr, offs, capS, n_nodes, nbkt);

        // spmm: 2 bucket-range dispatches (keeps top-5 visibility threshold ~108us)
        int b0 = 0;
        for (int sseg = 1; sseg <= 2; ++sseg) {
            int b1 = (sseg == 2) ? nbkt : ((nbkt / 2) & ~7);
            if (b1 <= b0) continue;
            int grid = 8 * (((b1 - b0) + 7) / 8) * 64;
            spmm_bf16_kernel<1><<<grid, THREADS, 0, stream>>>(
                (const uint2*)xb, offs, pr, aggb, b0, b1, n_nodes);
            b0 = b1;
        }
        int gb = (n_nodes + 127) / 128;
        gemm_direct3_kernel<<<gb, THREADS, 0, stream>>>(aggb, WbP, bias, out, n_nodes);
    } else {
        // -------- fallback: round-4 path --------
        int nb = (n_nodes + 1023) >> 10;
        size_t Af = (size_t)((n_nodes + 63) & ~63);
        int* cnt   = (int*)d_ws;
        int* offsf = cnt + Af;
        int* cur   = offsf + Af;
        int* bsum  = cur + Af;
        int* wbase = bsum + (((size_t)nb + 64) & ~63ull);
        unsigned short* Wbf = (unsigned short*)wbase;
        int2* prf  = (int2*)(Wbf + 65536);
        int* aft   = (int*)(prf + n_edges);
        unsigned short* xbf = (unsigned short*)aft;
        size_t need_old = (size_t)((char*)(xbf + (size_t)n_nodes * 256) - (char*)d_ws);
        bool told = ws_size >= need_old;

        zero_kernel<<<(n_nodes + THREADS - 1) / THREADS, THREADS, 0, stream>>>(cnt, n_nodes);
        hist_part_kernel<<<2048, THREADS, 0, stream>>>(erow, cnt, n_edges, n_nodes);
        scan1_kernel<<<nb, THREADS, 0, stream>>>(cnt, offsf, bsum, n_nodes);
        scan2_kernel<<<1, THREADS, 0, stream>>>(bsum, nb);
        scan3_kernel<<<(n_nodes + THREADS - 1) / THREADS, THREADS, 0, stream>>>(offsf, bsum, cur, n_nodes);
        place_part_kernel<<<2048, THREADS, 0, stream>>>(erow, ecol, evalv, cur, prf, n_edges, n_nodes);
        cvt_bf16_kernel<<<32, THREADS, 0, stream>>>((const float4*)W, (uint4*)Wbf, 65536 / 8);

        int gb = (n_nodes + 63) / 64;
        if (told) {
            int n8 = n_nodes * 32;
            cvt_bf16_kernel<<<(n8 + THREADS - 1) / THREADS, THREADS, 0, stream>>>(
                (const float4*)x, (uint4*)xbf, n8);
            int nbf = (n_nodes + 255) / 256;
            int gridf = 8 * ((nbf + 7) / 8) * 64;
            spmm_bf16_kernel<0><<<gridf, THREADS, 0, stream>>>(
                (const uint2*)xbf, offsf, prf, out, 0, nbf, n_nodes);
        } else {
            int spmm_blocks_f = (n_nodes + 3) / 4;
            spmm_f32_kernel<<<spmm_blocks_f, THREADS, 0, stream>>>(
                (const float4*)x, offsf, prf, (float4*)out, n_nodes);
        }
        gemm_mfma_kernel<<<gb, THREADS, 0, stream>>>(out, Wbf, bias, n_nodes);
    }
}

// Round 14
// 421.965 us; speedup vs baseline: 1.0249x; 1.0249x over previous
//
#include <hip/hip_runtime.h>

#define THREADS 256
#define P2T 512
#define P1B 1024     // p1 blocks
#define MAXEPB 3200  // max edges per p1 block (LDS presort capacity)
#define CVTXB 1536

typedef __attribute__((ext_vector_type(8))) short short8;
typedef __attribute__((ext_vector_type(4))) float f32x4;

__device__ __forceinline__ unsigned short f2bf(float f) {
    unsigned u = __builtin_bit_cast(unsigned, f);
    return (unsigned short)((u + 0x7FFFu + ((u >> 16) & 1u)) >> 16);  // RNE
}
__device__ __forceinline__ float bf2f_lo(unsigned u) { return __builtin_bit_cast(float, u << 16); }
__device__ __forceinline__ float bf2f_hi(unsigned u) { return __builtin_bit_cast(float, u & 0xFFFF0000u); }

// ---------------- p1: LDS-presort counting pass -> coalesced estage write-out ----------
// r13 diagnosis: per-lane scattered 8B global stores serialize on the address
// coalescer (64 lines/wave-store). Here records are sorted in LDS first, then
// written out with consecutive lanes -> consecutive addresses (full lines).
__global__ __launch_bounds__(THREADS)
void p1_presort_kernel(const int* __restrict__ row, const int* __restrict__ col,
                       const float* __restrict__ val, int* __restrict__ gcur,
                       uint2* __restrict__ estage, int n_edges, int nbkt, int capS) {
    __shared__ int h[512];
    __shared__ int base[512];
    __shared__ int gchunk[512];
    __shared__ int curl[512];
    __shared__ int wsum[4];
    __shared__ uint2 rec[MAXEPB];
    __shared__ unsigned short rbkt[MAXEPB];

    int b = blockIdx.x, tid = threadIdx.x;
    int g = b & 7;
    int E0 = (int)((long long)b * n_edges / P1B);
    int E1 = (int)((long long)(b + 1) * n_edges / P1B);
    int cnt = E1 - E0;

    h[2 * tid] = 0; h[2 * tid + 1] = 0;
    __syncthreads();
    // pass A: local histogram
    for (int e = E0 + tid; e < E1; e += THREADS)
        atomicAdd(&h[row[e] >> 8], 1);
    __syncthreads();
    // local exclusive scan of h[0..511] (2 entries/thread)
    int v0 = h[2 * tid], v1 = h[2 * tid + 1];
    int ts = v0 + v1;
    int lane = tid & 63, w = tid >> 6;
    int incl = ts;
    #pragma unroll
    for (int off = 1; off < 64; off <<= 1) {
        int t = __shfl_up(incl, off, 64);
        if (lane >= off) incl += t;
    }
    if (lane == 63) wsum[w] = incl;
    __syncthreads();
    int wo = 0;
    for (int i = 0; i < w; ++i) wo += wsum[i];
    int excl = wo + incl - ts;
    base[2 * tid] = excl;
    base[2 * tid + 1] = excl + v0;
    curl[2 * tid] = excl;
    curl[2 * tid + 1] = excl + v0;
    // reserve global chunks (one atomic per nonzero bucket)
    #pragma unroll
    for (int q = 0; q < 2; ++q) {
        int bk = 2 * tid + q;
        if (bk < nbkt) {
            int c = h[bk];
            int ro = c ? atomicAdd(&gcur[bk * 8 + g], c) : 0;
            gchunk[bk] = (bk * 8 + g) * capS + ro;
        }
    }
    __syncthreads();
    // pass B: scatter records into LDS (sorted by bucket)
    for (int e = E0 + tid; e < E1; e += THREADS) {
        int r = row[e];
        int bk = r >> 8;
        int pos = atomicAdd(&curl[bk], 1);
        rec[pos] = make_uint2(((unsigned)(r & 255) << 24) | (unsigned)col[e],
                              (unsigned)__float_as_int(val[e]));
        rbkt[pos] = (unsigned short)bk;
    }
    __syncthreads();
    // pass C: coalesced write-out (consecutive i -> consecutive dst within runs)
    for (int i = tid; i < cnt; i += THREADS) {
        int bk = rbkt[i];
        int dst = gchunk[bk] + (i - base[bk]);
        if (dst < (bk * 8 + g + 1) * capS)   // overflow guard
            estage[dst] = rec[i];
    }
}

// ---------------- cvtWX: W pack (32 blocks) + x convert (grid-stride) ----------------
__global__ void cvtWX_kernel(const float* __restrict__ W, unsigned short* __restrict__ WbP,
                             const float4* __restrict__ x, uint4* __restrict__ xb, int n8) {
    int b = blockIdx.x, tid = threadIdx.x;
    if (b < 32) {
        int f = b * THREADS + tid;                  // 8192 frags
        int l = f & 63, nt = (f >> 6) & 15, k0i = f >> 10;
        int r = nt * 16 + (l & 15);
        int koff = k0i * 32 + 8 * (l >> 4);
        const float4* s = reinterpret_cast<const float4*>(W + r * 256 + koff);
        float4 a = s[0], bb = s[1];
        uint4 o;
        o.x = (unsigned)f2bf(a.x) | ((unsigned)f2bf(a.y) << 16);
        o.y = (unsigned)f2bf(a.z) | ((unsigned)f2bf(a.w) << 16);
        o.z = (unsigned)f2bf(bb.x) | ((unsigned)f2bf(bb.y) << 16);
        o.w = (unsigned)f2bf(bb.z) | ((unsigned)f2bf(bb.w) << 16);
        reinterpret_cast<uint4*>(WbP)[f] = o;
    } else {
        int stride = CVTXB * THREADS;
        for (int i = (b - 32) * THREADS + tid; i < n8; i += stride) {
            float4 a = x[2 * i], bb = x[2 * i + 1];
            uint4 o;
            o.x = (unsigned)f2bf(a.x) | ((unsigned)f2bf(a.y) << 16);
            o.y = (unsigned)f2bf(a.z) | ((unsigned)f2bf(a.w) << 16);
            o.z = (unsigned)f2bf(bb.x) | ((unsigned)f2bf(bb.y) << 16);
            o.w = (unsigned)f2bf(bb.z) | ((unsigned)f2bf(bb.w) << 16);
            reinterpret_cast<uint4*>(xb)[i] = o;
        }
    }
}

// ---------------- p2: per-bucket sort -> CSR over 8 XCD sub-regions ----------------
__global__ void p2_sort(const uint2* __restrict__ estage, const int* __restrict__ gcur,
                        int2* __restrict__ pr, int* __restrict__ offs,
                        int capS, int n_nodes, int nbkt) {
    __shared__ int red[P2T];
    __shared__ int h[256];
    __shared__ int curh[256];
    __shared__ int wsum[4];
    __shared__ int scnt[8];
    int b = blockIdx.x, tid = threadIdx.x;

    int lim = b * 8;
    int partial = 0;
    for (int j = tid; j < lim; j += P2T) {
        int c = gcur[j];
        partial += c > capS ? capS : c;
    }
    red[tid] = partial;
    __syncthreads();
    #pragma unroll
    for (int s = P2T / 2; s > 0; s >>= 1) {
        if (tid < s) red[tid] += red[tid + s];
        __syncthreads();
    }
    int gb = red[0];
    if (tid < 8) {
        int c = gcur[b * 8 + tid];
        scnt[tid] = c > capS ? capS : c;
    }
    if (tid < 256) h[tid] = 0;
    __syncthreads();

    #pragma unroll
    for (int g = 0; g < 8; ++g) {
        int cnt = scnt[g];
        int base = (b * 8 + g) * capS;
        for (int i = tid; i < cnt; i += P2T)
            atomicAdd(&h[estage[base + i].x >> 24], 1);
    }
    __syncthreads();
    if (tid < 256) {
        int v = h[tid];
        int lane = tid & 63, w = tid >> 6;
        int incl = v;
        #pragma unroll
        for (int off = 1; off < 64; off <<= 1) {
            int t = __shfl_up(incl, off, 64);
            if (lane >= off) incl += t;
        }
        if (lane == 63) wsum[w] = incl;
        __syncthreads();
        int wo = 0;
        for (int i = 0; i < w; ++i) wo += wsum[i];
        int excl = wo + incl - v;
        int node = b * 256 + tid;
        if (node < n_nodes) offs[node] = gb + excl;
        curh[tid] = gb + excl;
    } else {
        __syncthreads();
    }
    if (b == nbkt - 1 && tid == 0) {
        int t = 0;
        #pragma unroll
        for (int g = 0; g < 8; ++g) t += scnt[g];
        offs[n_nodes] = gb + t;
    }
    __syncthreads();
    #pragma unroll
    for (int g = 0; g < 8; ++g) {
        int cnt = scnt[g];
        int base = (b * 8 + g) * capS;
        for (int i = tid; i < cnt; i += P2T) {
            uint2 p = estage[base + i];
            int q = atomicAdd(&curh[(int)(p.x >> 24)], 1);   // LDS atomic
            pr[q] = make_int2((int)(p.x & 0x00FFFFFFu), (int)p.y);
        }
    }
}

// ---------------- SpMM: one wave64 per node; bucket-range [b0,b1) ----------------
template<int OUT_BF16>
__global__ void spmm_bf16_kernel(const uint2* __restrict__ xb, const int* __restrict__ offs,
                                 const int2* __restrict__ pr, void* __restrict__ outp,
                                 int b0, int b1, int nnodes) {
    int g = blockIdx.x & 7;
    int inst = blockIdx.x >> 3;
    int bkt = b0 + g + 8 * (inst >> 6);
    if (bkt >= b1) return;
    int wid = bkt * 256 + (inst & 63) * 4 + (threadIdx.x >> 6);
    int lane = threadIdx.x & 63;
    if (wid >= nnodes) return;
    int s = offs[wid], e = offs[wid + 1];
    float a0 = 0.f, a1 = 0.f, a2 = 0.f, a3 = 0.f;
    int i = s;
    if (i < e && (i & 1)) {
        int2 p = pr[i];
        uint2 xv = xb[(size_t)p.x * 64 + lane];
        float v = __int_as_float(p.y);
        a0 = fmaf(v, bf2f_lo(xv.x), a0); a1 = fmaf(v, bf2f_hi(xv.x), a1);
        a2 = fmaf(v, bf2f_lo(xv.y), a2); a3 = fmaf(v, bf2f_hi(xv.y), a3);
        ++i;
    }
    for (; i + 8 <= e; i += 8) {
        int4 pa = *reinterpret_cast<const int4*>(pr + i);
        int4 pb = *reinterpret_cast<const int4*>(pr + i + 2);
        int4 pc = *reinterpret_cast<const int4*>(pr + i + 4);
        int4 pd = *reinterpret_cast<const int4*>(pr + i + 6);
        uint2 x0 = xb[(size_t)pa.x * 64 + lane];
        uint2 x1 = xb[(size_t)pa.z * 64 + lane];
        uint2 x2 = xb[(size_t)pb.x * 64 + lane];
        uint2 x3 = xb[(size_t)pb.z * 64 + lane];
        uint2 x4_ = xb[(size_t)pc.x * 64 + lane];
        uint2 x5 = xb[(size_t)pc.z * 64 + lane];
        uint2 x6 = xb[(size_t)pd.x * 64 + lane];
        uint2 x7 = xb[(size_t)pd.z * 64 + lane];
        float v0 = __int_as_float(pa.y), v1 = __int_as_float(pa.w);
        float v2 = __int_as_float(pb.y), v3 = __int_as_float(pb.w);
        float v4 = __int_as_float(pc.y), v5 = __int_as_float(pc.w);
        float v6 = __int_as_float(pd.y), v7 = __int_as_float(pd.w);
        a0 = fmaf(v0, bf2f_lo(x0.x), a0); a1 = fmaf(v0, bf2f_hi(x0.x), a1);
        a2 = fmaf(v0, bf2f_lo(x0.y), a2); a3 = fmaf(v0, bf2f_hi(x0.y), a3);
        a0 = fmaf(v1, bf2f_lo(x1.x), a0); a1 = fmaf(v1, bf2f_hi(x1.x), a1);
        a2 = fmaf(v1, bf2f_lo(x1.y), a2); a3 = fmaf(v1, bf2f_hi(x1.y), a3);
        a0 = fmaf(v2, bf2f_lo(x2.x), a0); a1 = fmaf(v2, bf2f_hi(x2.x), a1);
        a2 = fmaf(v2, bf2f_lo(x2.y), a2); a3 = fmaf(v2, bf2f_hi(x2.y), a3);
        a0 = fmaf(v3, bf2f_lo(x3.x), a0); a1 = fmaf(v3, bf2f_hi(x3.x), a1);
        a2 = fmaf(v3, bf2f_lo(x3.y), a2); a3 = fmaf(v3, bf2f_hi(x3.y), a3);
        a0 = fmaf(v4, bf2f_lo(x4_.x), a0); a1 = fmaf(v4, bf2f_hi(x4_.x), a1);
        a2 = fmaf(v4, bf2f_lo(x4_.y), a2); a3 = fmaf(v4, bf2f_hi(x4_.y), a3);
        a0 = fmaf(v5, bf2f_lo(x5.x), a0); a1 = fmaf(v5, bf2f_hi(x5.x), a1);
        a2 = fmaf(v5, bf2f_lo(x5.y), a2); a3 = fmaf(v5, bf2f_hi(x5.y), a3);
        a0 = fmaf(v6, bf2f_lo(x6.x), a0); a1 = fmaf(v6, bf2f_hi(x6.x), a1);
        a2 = fmaf(v6, bf2f_lo(x6.y), a2); a3 = fmaf(v6, bf2f_hi(x6.y), a3);
        a0 = fmaf(v7, bf2f_lo(x7.x), a0); a1 = fmaf(v7, bf2f_hi(x7.x), a1);
        a2 = fmaf(v7, bf2f_lo(x7.y), a2); a3 = fmaf(v7, bf2f_hi(x7.y), a3);
    }
    for (; i + 2 <= e; i += 2) {
        int4 pa = *reinterpret_cast<const int4*>(pr + i);
        uint2 x0 = xb[(size_t)pa.x * 64 + lane];
        uint2 x1 = xb[(size_t)pa.z * 64 + lane];
        float v0 = __int_as_float(pa.y), v1 = __int_as_float(pa.w);
        a0 = fmaf(v0, bf2f_lo(x0.x), a0); a1 = fmaf(v0, bf2f_hi(x0.x), a1);
        a2 = fmaf(v0, bf2f_lo(x0.y), a2); a3 = fmaf(v0, bf2f_hi(x0.y), a3);
        a0 = fmaf(v1, bf2f_lo(x1.x), a0); a1 = fmaf(v1, bf2f_hi(x1.x), a1);
        a2 = fmaf(v1, bf2f_lo(x1.y), a2); a3 = fmaf(v1, bf2f_hi(x1.y), a3);
    }
    for (; i < e; ++i) {
        int2 p = pr[i];
        uint2 xv = xb[(size_t)p.x * 64 + lane];
        float v = __int_as_float(p.y);
        a0 = fmaf(v, bf2f_lo(xv.x), a0); a1 = fmaf(v, bf2f_hi(xv.x), a1);
        a2 = fmaf(v, bf2f_lo(xv.y), a2); a3 = fmaf(v, bf2f_hi(xv.y), a3);
    }
    if (OUT_BF16) {
        ushort4 o;
        o.x = f2bf(a0); o.y = f2bf(a1); o.z = f2bf(a2); o.w = f2bf(a3);
        *reinterpret_cast<ushort4*>((unsigned short*)outp + (size_t)wid * 256 + 4 * lane) = o;
    } else {
        ((float4*)outp)[(size_t)wid * 64 + lane] = make_float4(a0, a1, a2, a3);
    }
}

__global__ void spmm_f32_kernel(const float4* __restrict__ x4, const int* __restrict__ offs,
                                const int2* __restrict__ pr, float4* __restrict__ out4,
                                int nnodes) {
    int wid = (blockIdx.x * blockDim.x + threadIdx.x) >> 6;
    int lane = threadIdx.x & 63;
    if (wid >= nnodes) return;
    int s = offs[wid], e = offs[wid + 1];
    float4 acc = make_float4(0.f, 0.f, 0.f, 0.f);
    for (int i = s; i < e; ++i) {
        int2 p = pr[i];
        float4 xv = x4[(size_t)p.x * 64 + lane];
        float v = __int_as_float(p.y);
        acc.x = fmaf(v, xv.x, acc.x); acc.y = fmaf(v, xv.y, acc.y);
        acc.z = fmaf(v, xv.z, acc.z); acc.w = fmaf(v, xv.w, acc.w);
    }
    out4[(size_t)wid * 64 + lane] = acc;
}

// ---------------- gemm_direct3: 2 row-tiles share B-frags, N-split keeps VGPR low ----
__launch_bounds__(256)
__global__ void gemm_direct3_kernel(const unsigned short* __restrict__ aggb,
                                    const unsigned short* __restrict__ WbP,
                                    const float* __restrict__ bias,
                                    float* __restrict__ out, int n) {
    int tid = threadIdx.x, lane = tid & 63, w = tid >> 6;
    int row0 = blockIdx.x * 128 + w * 32;
    int lr = lane & 15, lg = lane >> 4;
    const unsigned short* arow0 = aggb + (size_t)(row0 + lr) * 256 + lg * 8;
    const unsigned short* arow1 = arow0 + 16 * 256;
    short8 af0[8], af1[8];
    #pragma unroll
    for (int k = 0; k < 8; ++k) {
        af0[k] = *reinterpret_cast<const short8*>(arow0 + k * 32);
        af1[k] = *reinterpret_cast<const short8*>(arow1 + k * 32);
    }
    #pragma unroll
    for (int half = 0; half < 2; ++half) {
        f32x4 acc0[8], acc1[8];
        #pragma unroll
        for (int nt = 0; nt < 8; ++nt) {
            acc0[nt] = (f32x4){0.f, 0.f, 0.f, 0.f};
            acc1[nt] = (f32x4){0.f, 0.f, 0.f, 0.f};
        }
        #pragma unroll
        for (int k = 0; k < 8; ++k) {
            #pragma unroll
            for (int nt = 0; nt < 8; ++nt) {
                short8 bf_ = *reinterpret_cast<const short8*>(
                    &WbP[(size_t)((k * 16 + half * 8 + nt) * 64 + lane) * 8]);
                acc0[nt] = __builtin_amdgcn_mfma_f32_16x16x32_bf16(af0[k], bf_, acc0[nt], 0, 0, 0);
                acc1[nt] = __builtin_amdgcn_mfma_f32_16x16x32_bf16(af1[k], bf_, acc1[nt], 0, 0, 0);
            }
        }
        #pragma unroll
        for (int nt = 0; nt < 8; ++nt) {
            int gc = half * 128 + nt * 16 + lr;
            float bv = bias[gc];
            #pragma unroll
            for (int q = 0; q < 4; ++q) {
                int gr0 = row0 + lg * 4 + q;
                int gr1 = gr0 + 16;
                if (gr0 < n) out[(size_t)gr0 * 256 + gc] = acc0[nt][q] + bv;
                if (gr1 < n) out[(size_t)gr1 * 256 + gc] = acc1[nt][q] + bv;
            }
        }
    }
}

// ---------------- fallback tier (round-4 path) ----------------

__global__ void zero_kernel(int* __restrict__ p, int n) {
    int i = blockIdx.x * blockDim.x + threadIdx.x;
    if (i < n) p[i] = 0;
}

__global__ void hist_part_kernel(const int* __restrict__ row, int* __restrict__ cnt,
                                 int n_edges, int n_nodes) {
    int g = blockIdx.x & 7;
    int inst = blockIdx.x >> 3;
    int ninst = gridDim.x >> 3;
    int lo = (int)(((long long)g * n_nodes) >> 3);
    int hi = (int)(((long long)(g + 1) * n_nodes) >> 3);
    int e0 = (int)(((long long)inst * n_edges) / ninst);
    int e1 = (int)(((long long)(inst + 1) * n_edges) / ninst);
    for (int e = e0 + threadIdx.x; e < e1; e += THREADS) {
        int r = row[e];
        if (r >= lo && r < hi) atomicAdd(&cnt[r], 1);
    }
}

__global__ void place_part_kernel(const int* __restrict__ row, const int* __restrict__ col,
                                  const float* __restrict__ val, int* __restrict__ cur,
                                  int2* __restrict__ pr, int n_edges, int n_nodes) {
    int g = blockIdx.x & 7;
    int inst = blockIdx.x >> 3;
    int ninst = gridDim.x >> 3;
    int lo = (int)(((long long)g * n_nodes) >> 3);
    int hi = (int)(((long long)(g + 1) * n_nodes) >> 3);
    int e0 = (int)(((long long)inst * n_edges) / ninst);
    int e1 = (int)(((long long)(inst + 1) * n_edges) / ninst);
    for (int e = e0 + threadIdx.x; e < e1; e += THREADS) {
        int r = row[e];
        if (r >= lo && r < hi) {
            int p = atomicAdd(&cur[r], 1);
            pr[p] = make_int2(col[e], __float_as_int(val[e]));
        }
    }
}

__global__ void scan1_kernel(const int* __restrict__ cnt, int* __restrict__ offs,
                             int* __restrict__ bsum, int n) {
    int tid = threadIdx.x;
    int base = blockIdx.x * 1024 + tid * 4;
    int v0 = 0, v1 = 0, v2 = 0, v3 = 0;
    if (base + 3 < n) {
        int4 v = *reinterpret_cast<const int4*>(cnt + base);
        v0 = v.x; v1 = v.y; v2 = v.z; v3 = v.w;
    } else {
        if (base + 0 < n) v0 = cnt[base + 0];
        if (base + 1 < n) v1 = cnt[base + 1];
        if (base + 2 < n) v2 = cnt[base + 2];
    }
    int ts = v0 + v1 + v2 + v3;
    int lane = tid & 63;
    int incl = ts;
    #pragma unroll
    for (int off = 1; off < 64; off <<= 1) {
        int t = __shfl_up(incl, off, 64);
        if (lane >= off) incl += t;
    }
    __shared__ int wsum[4];
    int w = tid >> 6;
    if (lane == 63) wsum[w] = incl;
    __syncthreads();
    int wo = 0;
    for (int i = 0; i < w; ++i) wo += wsum[i];
    int excl = wo + incl - ts;
    if (base + 0 < n) offs[base + 0] = excl;
    if (base + 1 < n) offs[base + 1] = excl + v0;
    if (base + 2 < n) offs[base + 2] = excl + v0 + v1;
    if (base + 3 < n) offs[base + 3] = excl + v0 + v1 + v2;
    if (tid == THREADS - 1) bsum[blockIdx.x] = wo + incl;
}

__global__ void scan2_kernel(int* __restrict__ bsum, int nb) {
    int tid = threadIdx.x;
    int base = tid * 4;
    int v0 = 0, v1 = 0, v2 = 0, v3 = 0;
    if (base + 0 < nb) v0 = bsum[base + 0];
    if (base + 1 < nb) v1 = bsum[base + 1];
    if (base + 2 < nb) v2 = bsum[base + 2];
    if (base + 3 < nb) v3 = bsum[base + 3];
    int ts = v0 + v1 + v2 + v3;
    int lane = tid & 63;
    int incl = ts;
    #pragma unroll
    for (int off = 1; off < 64; off <<= 1) {
        int t = __shfl_up(incl, off, 64);
        if (lane >= off) incl += t;
    }
    __shared__ int wsum[4];
    int w = tid >> 6;
    if (lane == 63) wsum[w] = incl;
    __syncthreads();
    int wo = 0;
    for (int i = 0; i < w; ++i) wo += wsum[i];
    int excl = wo + incl - ts;
    if (base + 0 < nb) bsum[base + 0] = excl;
    if (base + 1 < nb) bsum[base + 1] = excl + v0;
    if (base + 2 < nb) bsum[base + 2] = excl + v0 + v1;
    if (base + 3 < nb) bsum[base + 3] = excl + v0 + v1 + v2;
    if (tid == THREADS - 1) bsum[nb] = wo + incl;
}

__global__ void scan3_kernel(int* __restrict__ offs, const int* __restrict__ bsum,
                             int* __restrict__ cur, int n) {
    int i = blockIdx.x * blockDim.x + threadIdx.x;
    if (i < n) {
        int v = offs[i] + bsum[i >> 10];
        offs[i] = v;
        cur[i] = v;
    }
    if (i == 0) offs[n] = bsum[(n + 1023) >> 10];
}

__global__ void cvt_bf16_kernel(const float4* __restrict__ in, uint4* __restrict__ out, int n8) {
    int i = blockIdx.x * blockDim.x + threadIdx.x;
    if (i >= n8) return;
    float4 a = in[2 * i], b = in[2 * i + 1];
    uint4 o;
    o.x = (unsigned)f2bf(a.x) | ((unsigned)f2bf(a.y) << 16);
    o.y = (unsigned)f2bf(a.z) | ((unsigned)f2bf(a.w) << 16);
    o.z = (unsigned)f2bf(b.x) | ((unsigned)f2bf(b.y) << 16);
    o.w = (unsigned)f2bf(b.z) | ((unsigned)f2bf(b.w) << 16);
    out[i] = o;
}

__launch_bounds__(256, 2)
__global__ void gemm_mfma_kernel(float* __restrict__ out, const unsigned short* __restrict__ Wb,
                                 const float* __restrict__ bias, int nrows) {
    __shared__ unsigned short As[64][264];
    __shared__ unsigned short Ws[256][40];
    int tid = threadIdx.x;
    int rowBase = blockIdx.x * 64;

    const float4* o4 = reinterpret_cast<const float4*>(out);
    for (int it = tid; it < 64 * 64; it += 256) {
        int r = it >> 6, c = it & 63;
        float4 v = make_float4(0.f, 0.f, 0.f, 0.f);
        int gr = rowBase + r;
        if (gr < nrows) v = o4[(size_t)gr * 64 + c];
        ushort4 w;
        w.x = f2bf(v.x); w.y = f2bf(v.y); w.z = f2bf(v.z); w.w = f2bf(v.w);
        *reinterpret_cast<ushort4*>(&As[r][c * 4]) = w;
    }

    int w = tid >> 6, lane = tid & 63;
    int lr = lane & 15, lg = lane >> 4;
    f32x4 acc[16];
    #pragma unroll
    for (int nt = 0; nt < 16; ++nt) acc[nt] = (f32x4){0.f, 0.f, 0.f, 0.f};

    for (int k0 = 0; k0 < 256; k0 += 32) {
        __syncthreads();
        for (int it = tid; it < 1024; it += 256) {
            int r = it >> 2, c = it & 3;
            uint4 v = *reinterpret_cast<const uint4*>(Wb + (size_t)r * 256 + k0 + c * 8);
            *reinterpret_cast<uint4*>(&Ws[r][c * 8]) = v;
        }
        __syncthreads();
        short8 af = *reinterpret_cast<const short8*>(&As[w * 16 + lr][k0 + 8 * lg]);
        #pragma unroll
        for (int nt = 0; nt < 16; ++nt) {
            short8 bf_ = *reinterpret_cast<const short8*>(&Ws[nt * 16 + lr][8 * lg]);
            acc[nt] = __builtin_amdgcn_mfma_f32_16x16x32_bf16(af, bf_, acc[nt], 0, 0, 0);
        }
    }

    #pragma unroll
    for (int nt = 0; nt < 16; ++nt) {
        int gc = nt * 16 + lr;
        float bv = bias[gc];
        #pragma unroll
        for (int q = 0; q < 4; ++q) {
            int gr = rowBase + w * 16 + lg * 4 + q;
            if (gr < nrows) out[(size_t)gr * 256 + gc] = acc[nt][q] + bv;
        }
    }
}

// ---------------- launch ----------------

extern "C" void kernel_launch(void* const* d_in, const int* in_sizes, int n_in,
                              void* d_out, int out_size, void* d_ws, size_t ws_size,
                              hipStream_t stream) {
    const float* x     = (const float*)d_in[0];
    const int*   erow  = (const int*)d_in[1];
    const int*   ecol  = (const int*)d_in[2];
    const float* evalv = (const float*)d_in[3];
    const float* W     = (const float*)d_in[4];
    const float* bias  = (const float*)d_in[5];
    float* out = (float*)d_out;

    int n_nodes = in_sizes[0] / 256;
    int n_edges = in_sizes[1];

    int nbkt = (n_nodes + 255) >> 8;
    int avg8 = n_edges / (8 * (nbkt > 0 ? nbkt : 1)) + 1;
    int capS = avg8 + avg8 / 8 + 512;

    // ---- workspace layout (int units) ----
    size_t A = (size_t)((n_nodes + 63) & ~63) + 64;
    int* offs  = (int*)d_ws;
    int* gcur  = offs + A;                                // 4096 sub-region cursors
    unsigned short* WbP = (unsigned short*)(gcur + 4096); // 32768 ints
    int2* pr = (int2*)(WbP + 65536);                      // E records
    int* after_pr = (int*)(pr + n_edges);

    size_t est_ints  = (size_t)nbkt * 8 * capS * 2;
    size_t aggb_ints = (size_t)n_nodes * 128 + 32768;
    size_t xb_ints   = (size_t)n_nodes * 128;
    size_t alias_ints = est_ints > aggb_ints ? est_ints : aggb_ints;
    size_t head_ints = (size_t)(after_pr - (int*)d_ws);
    size_t need_new = (head_ints + alias_ints + xb_ints) * 4;
    bool new_ok = (nbkt <= 512) && (nbkt >= 1) && (n_nodes <= (1 << 24)) &&
                  (n_edges <= P1B * (MAXEPB - 64)) && ws_size >= need_new;

    if (new_ok) {
        uint2* estage = (uint2*)after_pr;
        unsigned short* aggb = (unsigned short*)after_pr;   // alias (estage dead post-p2)
        unsigned short* xb = (unsigned short*)(after_pr + alias_ints);

        hipMemsetAsync(gcur, 0, 4096 * sizeof(int), stream);
        int n8 = n_nodes * 32;
        cvtWX_kernel<<<32 + CVTXB, THREADS, 0, stream>>>(
            W, WbP, (const float4*)x, (uint4*)xb, n8);
        p1_presort_kernel<<<P1B, THREADS, 0, stream>>>(
            erow, ecol, evalv, gcur, estage, n_edges, nbkt, capS);
        p2_sort<<<nbkt, P2T, 0, stream>>>(estage, gcur, pr, offs, capS, n_nodes, nbkt);

        int grid = 8 * ((nbkt + 7) / 8) * 64;
        spmm_bf16_kernel<1><<<grid, THREADS, 0, stream>>>(
            (const uint2*)xb, offs, pr, aggb, 0, nbkt, n_nodes);
        int gb = (n_nodes + 127) / 128;
        gemm_direct3_kernel<<<gb, THREADS, 0, stream>>>(aggb, WbP, bias, out, n_nodes);
    } else {
        // -------- fallback: round-4 path --------
        int nb = (n_nodes + 1023) >> 10;
        size_t Af = (size_t)((n_nodes + 63) & ~63);
        int* cnt   = (int*)d_ws;
        int* offsf = cnt + Af;
        int* cur   = offsf + Af;
        int* bsum  = cur + Af;
        int* wbase = bsum + (((size_t)nb + 64) & ~63ull);
        unsigned short* Wbf = (unsigned short*)wbase;
        int2* prf  = (int2*)(Wbf + 65536);
        int* aft   = (int*)(prf + n_edges);
        unsigned short* xbf = (unsigned short*)aft;
        size_t need_old = (size_t)((char*)(xbf + (size_t)n_nodes * 256) - (char*)d_ws);
        bool told = ws_size >= need_old;

        zero_kernel<<<(n_nodes + THREADS - 1) / THREADS, THREADS, 0, stream>>>(cnt, n_nodes);
        hist_part_kernel<<<2048, THREADS, 0, stream>>>(erow, cnt, n_edges, n_nodes);
        scan1_kernel<<<nb, THREADS, 0, stream>>>(cnt, offsf, bsum, n_nodes);
        scan2_kernel<<<1, THREADS, 0, stream>>>(bsum, nb);
        scan3_kernel<<<(n_nodes + THREADS - 1) / THREADS, THREADS, 0, stream>>>(offsf, bsum, cur, n_nodes);
        place_part_kernel<<<2048, THREADS, 0, stream>>>(erow, ecol, evalv, cur, prf, n_edges, n_nodes);
        cvt_bf16_kernel<<<32, THREADS, 0, stream>>>((const float4*)W, (uint4*)Wbf, 65536 / 8);

        int gb = (n_nodes + 63) / 64;
        if (told) {
            int n8 = n_nodes * 32;
            cvt_bf16_kernel<<<(n8 + THREADS - 1) / THREADS, THREADS, 0, stream>>>(
                (const float4*)x, (uint4*)xbf, n8);
            int nbf = (n_nodes + 255) / 256;
            int gridf = 8 * ((nbf + 7) / 8) * 64;
            spmm_bf16_kernel<0><<<gridf, THREADS, 0, stream>>>(
                (const uint2*)xbf, offsf, prf, out, 0, nbf, n_nodes);
        } else {
            int spmm_blocks_f = (n_nodes + 3) / 4;
            spmm_f32_kernel<<<spmm_blocks_f, THREADS, 0, stream>>>(
                (const float4*)x, offsf, prf, (float4*)out, n_nodes);
        }
        gemm_mfma_kernel<<<gb, THREADS, 0, stream>>>(out, Wbf, bias, n_nodes);
    }
}